// Round 5
// baseline (11780.275 us; speedup 1.0000x reference)
//
#include <hip/hip_runtime.h>

#define LSEQ 50
#define BATCH 256
#define DIN 256
#define LAT 512
#define HID 1024
#define ROWSTRIDE 257  // D_IN + 1 (dt channel)
#define NBLK 256

typedef __attribute__((ext_vector_type(8))) short s16x8;
typedef __attribute__((ext_vector_type(4))) float f32x4;
using u16 = unsigned short;

__device__ __forceinline__ u16 bfhi(float v) {
  union { float f; unsigned u; } a; a.f = v;
  return (u16)((a.u + 0x7FFFu + ((a.u >> 16) & 1u)) >> 16);
}
__device__ __forceinline__ void split2(float v, u16& h, u16& l) {
  u16 hu = bfhi(v);
  union { unsigned u; float f; } hf; hf.u = ((unsigned)hu) << 16;
  h = hu; l = bfhi(v - hf.f);
}
__device__ __forceinline__ float p2f(u16 h, u16 l) {
  union { unsigned u; float f; } a, b;
  a.u = ((unsigned)h) << 16; b.u = ((unsigned)l) << 16;
  return a.f + b.f;
}
__device__ __forceinline__ float sigmoidf_(float x) { return 1.f / (1.f + __expf(-x)); }
__device__ __forceinline__ f32x4 mfma16(s16x8 a, s16x8 b, f32x4 c) {
  return __builtin_amdgcn_mfma_f32_16x16x32_bf16(a, b, c, 0, 0, 0);
}
__device__ __forceinline__ ushort4 ldu4(const u16* p) { return *(const ushort4*)p; }
__device__ __forceinline__ void stu4(u16* p, ushort4 v) { *(ushort4*)p = v; }

// ---------- preprocessing ----------
// W[K][N] fp32 -> WT_hi[N][K], WT_lo[N][K] bf16 planes (transpose + split)
__global__ __launch_bounds__(256) void tsplit_k(const float* __restrict__ W,
    u16* __restrict__ Thi, u16* __restrict__ Tlo, int K, int N)
{
  __shared__ unsigned Ts[32][33];
  const int bk = blockIdx.x * 32, bn = blockIdx.y * 32;
  const int t = threadIdx.x;
  const int n_l = t & 31, k_l4 = (t >> 5) * 4;
  #pragma unroll
  for (int i = 0; i < 4; i++) {
    float v = W[(size_t)(bk + k_l4 + i) * N + bn + n_l];
    u16 h, l; split2(v, h, l);
    Ts[k_l4 + i][n_l] = ((unsigned)h << 16) | l;
  }
  __syncthreads();
  const int k_l = t & 31, n_l2 = t >> 5;
  #pragma unroll
  for (int i = 0; i < 4; i++) {
    int nn = n_l2 + 8 * i;
    unsigned u = Ts[k_l][nn];
    size_t o = (size_t)(bn + nn) * K + bk + k_l;
    Thi[o] = (u16)(u >> 16);
    Tlo[o] = (u16)(u & 0xFFFFu);
  }
}

__global__ __launch_bounds__(256) void esplit_k(const float* __restrict__ W,
    u16* __restrict__ Phi, u16* __restrict__ Plo)
{
  size_t i4 = ((size_t)blockIdx.x * 256 + threadIdx.x) * 4;
  float4 v = *(const float4*)&W[i4];
  u16 h[4], l[4];
  split2(v.x, h[0], l[0]); split2(v.y, h[1], l[1]);
  split2(v.z, h[2], l[2]); split2(v.w, h[3], l[3]);
  *(ushort4*)&Phi[i4] = make_ushort4(h[0], h[1], h[2], h[3]);
  *(ushort4*)&Plo[i4] = make_ushort4(l[0], l[1], l[2], l[3]);
}

__global__ __launch_bounds__(256) void init_k(u16* __restrict__ c0h,
    u16* __restrict__ c0l, unsigned* __restrict__ bar)
{
  size_t i4 = ((size_t)blockIdx.x * 256 + threadIdx.x) * 4;  // 256 blocks -> 256*1024
  *(ushort4*)&c0h[i4] = make_ushort4(0, 0, 0, 0);
  *(ushort4*)&c0l[i4] = make_ushort4(0, 0, 0, 0);
  if (blockIdx.x == 0 && threadIdx.x == 0) *bar = 0u;
}

// ---------- double-buffered split-bf16 GEMM phase (32x32 block tile) ----------
// EPI 1: O planes = split(tanh(acc + bias))      (h1 write)
// EPI 2: y = p2f(O planes) + (acc + bias)*dt/3; O planes = split(y)  (Euler)
template<int EPI>
__device__ __forceinline__ void gemm_phase(
    u16* Sah, u16* Sal, int sA, u16* Sbh, u16* Sbl, int sB,
    const u16* __restrict__ Ahi, const u16* __restrict__ Alo, int ldA, int m0,
    const u16* __restrict__ Bhi, const u16* __restrict__ Blo, int ldB, int n0,
    int K, const float* __restrict__ bias,
    u16* __restrict__ Ohi, u16* __restrict__ Olo,
    const float* __restrict__ data, int t, int tid)
{
  const int lane = tid & 63, wave = tid >> 6;
  const int wm = (wave >> 1) << 4, wn = (wave & 1) << 4;
  const int lr = lane & 15, lq = lane >> 4;
  const int srow = tid >> 3, sk4 = (tid & 7) << 2;
  const int sidx = srow * 40 + sk4;
  f32x4 acc = {0.f, 0.f, 0.f, 0.f};
  {
    size_t oa = (size_t)(m0 + srow) * ldA + sk4;
    size_t ob = (size_t)(n0 + srow) * ldB + sk4;
    stu4(&Sah[sidx], ldu4(&Ahi[oa])); stu4(&Sal[sidx], ldu4(&Alo[oa]));
    stu4(&Sbh[sidx], ldu4(&Bhi[ob])); stu4(&Sbl[sidx], ldu4(&Blo[ob]));
  }
  __syncthreads();
  const int niter = K >> 5;
  for (int it = 0; it < niter; ++it) {
    const int db = it & 1, nb = db ^ 1;
    const bool pf = (it + 1 < niter);
    ushort4 nah, nal, nbh, nbl;
    if (pf) {
      const int k0 = (it + 1) << 5;
      size_t oa = (size_t)(m0 + srow) * ldA + k0 + sk4;
      size_t ob = (size_t)(n0 + srow) * ldB + k0 + sk4;
      nah = ldu4(&Ahi[oa]); nal = ldu4(&Alo[oa]);
      nbh = ldu4(&Bhi[ob]); nbl = ldu4(&Blo[ob]);
    }
    const int fa = db * sA + (wm + lr) * 40 + lq * 8;
    const int fb = db * sB + (wn + lr) * 40 + lq * 8;
    s16x8 ah = *(const s16x8*)&Sah[fa];
    s16x8 al = *(const s16x8*)&Sal[fa];
    s16x8 bh = *(const s16x8*)&Sbh[fb];
    s16x8 bl = *(const s16x8*)&Sbl[fb];
    acc = mfma16(ah, bh, acc);
    acc = mfma16(ah, bl, acc);
    acc = mfma16(al, bh, acc);
    if (pf) {
      stu4(&Sah[nb * sA + sidx], nah); stu4(&Sal[nb * sA + sidx], nal);
      stu4(&Sbh[nb * sB + sidx], nbh); stu4(&Sbl[nb * sB + sidx], nbl);
    }
    __syncthreads();
  }
  #pragma unroll
  for (int r = 0; r < 4; ++r) {
    const int row = m0 + wm + lq * 4 + r;
    const int col = n0 + wn + lr;
    float v = acc[r] + bias[col];
    size_t o = (size_t)row * HID + col;
    if (EPI == 1) {
      float h1 = tanhf(v);
      u16 h, l; split2(h1, h, l);
      Ohi[o] = h; Olo[o] = l;
    } else {
      float dt3 = data[(size_t)(t * BATCH + row) * ROWSTRIDE + DIN] * (1.f / 3.f);
      float y = p2f(Ohi[o], Olo[o]) + v * dt3;
      u16 h, l; split2(y, h, l);
      Ohi[o] = h; Olo[o] = l;
    }
  }
}

struct MegaArgs {
  const float* data;
  const u16 *w1h, *w1l, *w2h, *w2l;
  const float *b1, *b2;
  const float* whh; const u16 *whhh, *whhl;
  const float* wih; const u16 *wihh, *wihl;
  const float *bih, *bhh;
  u16 *c0h, *c0l, *c1h, *c1l, *h1h, *h1l;
  unsigned* bar;
  float* out;
};

template<bool PLANES>
__global__ __launch_bounds__(256, 1) void mega_k(MegaArgs a)
{
  __shared__ u16 sAh[2 * 32 * 40], sAl[2 * 32 * 40];
  __shared__ u16 sBh[2 * 3 * 32 * 40], sBl[2 * 3 * 32 * 40];
  const int tid = threadIdx.x, bid = blockIdx.x;
  const int lane = tid & 63, wave = tid >> 6;
  const int wm = (wave >> 1) << 4, wn = (wave & 1) << 4;
  const int lr = lane & 15, lq = lane >> 4;
  const int srow = tid >> 3, sk4 = (tid & 7) << 2;
  const int sidx = srow * 40 + sk4;
  unsigned bcnt = 0;

  auto gbar = [&]() {
    __syncthreads();
    if (tid == 0) {
      __threadfence();
      atomicAdd(a.bar, 1u);
      const unsigned target = (bcnt + 1) * NBLK;
      while (__hip_atomic_load(a.bar, __ATOMIC_RELAXED, __HIP_MEMORY_SCOPE_AGENT) < target)
        __builtin_amdgcn_s_sleep(4);
      __threadfence();
    }
    bcnt++;
    __syncthreads();
  };

  for (int t = 0; t < LSEQ; ++t) {
    u16* chi = (t & 1) ? a.c1h : a.c0h;
    u16* clo = (t & 1) ? a.c1l : a.c0l;
    u16* nhi = (t & 1) ? a.c0h : a.c1h;
    u16* nlo = (t & 1) ? a.c0l : a.c1l;

    for (int s = 0; s < 3; ++s) {
      { // GEMM1 (all 256 blocks): h1 = tanh(y @ w1 + b1), y = cur cols 0..511
        const int m0 = (bid >> 5) << 5, n0 = (bid & 31) << 5;
        gemm_phase<1>(sAh, sAl, 1280, sBh, sBl, 3840,
                      chi, clo, HID, m0, a.w1h, a.w1l, 512, n0, 512,
                      a.b1, a.h1h, a.h1l, nullptr, 0, tid);
      }
      gbar();
      if (bid < 128) { // GEMM2: y += (h1 @ w2 + b2) * dt/3
        const int m0 = (bid >> 4) << 5, n0 = (bid & 15) << 5;
        gemm_phase<2>(sAh, sAl, 1280, sBh, sBl, 3840,
                      a.h1h, a.h1l, HID, m0, a.w2h, a.w2l, 1024, n0, 1024,
                      a.b2, chi, clo, a.data, t, tid);
      }
      gbar();
    }

    { // ---- fused GRU: gh (K=1024) + gi (K=256) + pointwise + outputs ----
      const int m0 = (bid >> 5) << 5, g0 = (bid & 31) << 5;
      f32x4 aR = {0,0,0,0}, aZ = {0,0,0,0}, aNh = {0,0,0,0}, aNi = {0,0,0,0};
      // phase 0 preload (K-tile 0)
      {
        size_t oa = (size_t)(m0 + srow) * HID + sk4;
        stu4(&sAh[sidx], ldu4(&chi[oa])); stu4(&sAl[sidx], ldu4(&clo[oa]));
        #pragma unroll
        for (int g = 0; g < 3; ++g) {
          const size_t rrow = (size_t)(g * 1024 + g0 + srow);
          if (PLANES) {
            size_t ob = rrow * 1024 + sk4;
            stu4(&sBh[g * 1280 + sidx], ldu4(&a.whhh[ob]));
            stu4(&sBl[g * 1280 + sidx], ldu4(&a.whhl[ob]));
          } else {
            float4 w4 = *(const float4*)&a.whh[rrow * 1024 + sk4];
            u16 h0,l0,h1,l1,h2,l2,h3,l3;
            split2(w4.x,h0,l0); split2(w4.y,h1,l1); split2(w4.z,h2,l2); split2(w4.w,h3,l3);
            stu4(&sBh[g * 1280 + sidx], make_ushort4(h0,h1,h2,h3));
            stu4(&sBl[g * 1280 + sidx], make_ushort4(l0,l1,l2,l3));
          }
        }
      }
      __syncthreads();
      for (int it = 0; it < 32; ++it) {
        const int db = it & 1, nb = db ^ 1;
        const bool pf = (it + 1 < 32);
        ushort4 nah, nal, nb0h, nb0l, nb1h, nb1l, nb2h, nb2l;
        if (pf) {
          const int k0 = (it + 1) << 5;
          size_t oa = (size_t)(m0 + srow) * HID + k0 + sk4;
          nah = ldu4(&chi[oa]); nal = ldu4(&clo[oa]);
          if (PLANES) {
            size_t r0 = (size_t)(0 * 1024 + g0 + srow) * 1024 + k0 + sk4;
            size_t r1 = (size_t)(1 * 1024 + g0 + srow) * 1024 + k0 + sk4;
            size_t r2 = (size_t)(2 * 1024 + g0 + srow) * 1024 + k0 + sk4;
            nb0h = ldu4(&a.whhh[r0]); nb0l = ldu4(&a.whhl[r0]);
            nb1h = ldu4(&a.whhh[r1]); nb1l = ldu4(&a.whhl[r1]);
            nb2h = ldu4(&a.whhh[r2]); nb2l = ldu4(&a.whhl[r2]);
          } else {
            #pragma unroll
            for (int g = 0; g < 3; ++g) {
              float4 w4 = *(const float4*)&a.whh[(size_t)(g * 1024 + g0 + srow) * 1024 + k0 + sk4];
              u16 h0,l0,h1,l1,h2,l2,h3,l3;
              split2(w4.x,h0,l0); split2(w4.y,h1,l1); split2(w4.z,h2,l2); split2(w4.w,h3,l3);
              ushort4 hh = make_ushort4(h0,h1,h2,h3), ll = make_ushort4(l0,l1,l2,l3);
              if (g == 0) { nb0h = hh; nb0l = ll; }
              else if (g == 1) { nb1h = hh; nb1l = ll; }
              else { nb2h = hh; nb2l = ll; }
            }
          }
        }
        const int fa = db * 1280 + (wm + lr) * 40 + lq * 8;
        s16x8 ah = *(const s16x8*)&sAh[fa];
        s16x8 al = *(const s16x8*)&sAl[fa];
        #pragma unroll
        for (int g = 0; g < 3; ++g) {
          const int fb = db * 3840 + g * 1280 + (wn + lr) * 40 + lq * 8;
          s16x8 bh = *(const s16x8*)&sBh[fb];
          s16x8 bl = *(const s16x8*)&sBl[fb];
          f32x4 c = (g == 0) ? aR : (g == 1) ? aZ : aNh;
          c = mfma16(ah, bh, c); c = mfma16(ah, bl, c); c = mfma16(al, bh, c);
          if (g == 0) aR = c; else if (g == 1) aZ = c; else aNh = c;
        }
        if (pf) {
          stu4(&sAh[nb * 1280 + sidx], nah); stu4(&sAl[nb * 1280 + sidx], nal);
          stu4(&sBh[nb * 3840 + 0 * 1280 + sidx], nb0h); stu4(&sBl[nb * 3840 + 0 * 1280 + sidx], nb0l);
          stu4(&sBh[nb * 3840 + 1 * 1280 + sidx], nb1h); stu4(&sBl[nb * 3840 + 1 * 1280 + sidx], nb1l);
          stu4(&sBh[nb * 3840 + 2 * 1280 + sidx], nb2h); stu4(&sBl[nb * 3840 + 2 * 1280 + sidx], nb2l);
        }
        __syncthreads();
      }
      // phase 1 preload (x_t split on the fly)
      {
        const float* xp = &a.data[(size_t)(t * BATCH + m0 + srow) * ROWSTRIDE + sk4];
        u16 xh[4], xl[4];
        #pragma unroll
        for (int i = 0; i < 4; i++) split2(xp[i], xh[i], xl[i]);
        stu4(&sAh[sidx], make_ushort4(xh[0], xh[1], xh[2], xh[3]));
        stu4(&sAl[sidx], make_ushort4(xl[0], xl[1], xl[2], xl[3]));
        #pragma unroll
        for (int g = 0; g < 3; ++g) {
          const size_t rrow = (size_t)(g * 1024 + g0 + srow);
          if (PLANES) {
            size_t ob = rrow * 256 + sk4;
            stu4(&sBh[g * 1280 + sidx], ldu4(&a.wihh[ob]));
            stu4(&sBl[g * 1280 + sidx], ldu4(&a.wihl[ob]));
          } else {
            float4 w4 = *(const float4*)&a.wih[rrow * 256 + sk4];
            u16 h0,l0,h1,l1,h2,l2,h3,l3;
            split2(w4.x,h0,l0); split2(w4.y,h1,l1); split2(w4.z,h2,l2); split2(w4.w,h3,l3);
            stu4(&sBh[g * 1280 + sidx], make_ushort4(h0,h1,h2,h3));
            stu4(&sBl[g * 1280 + sidx], make_ushort4(l0,l1,l2,l3));
          }
        }
      }
      __syncthreads();
      for (int it = 0; it < 8; ++it) {
        const int db = it & 1, nb = db ^ 1;
        const bool pf = (it + 1 < 8);
        ushort4 nah, nal, nb0h, nb0l, nb1h, nb1l, nb2h, nb2l;
        if (pf) {
          const int k0 = (it + 1) << 5;
          const float* xp = &a.data[(size_t)(t * BATCH + m0 + srow) * ROWSTRIDE + k0 + sk4];
          u16 xh[4], xl[4];
          #pragma unroll
          for (int i = 0; i < 4; i++) split2(xp[i], xh[i], xl[i]);
          nah = make_ushort4(xh[0], xh[1], xh[2], xh[3]);
          nal = make_ushort4(xl[0], xl[1], xl[2], xl[3]);
          if (PLANES) {
            size_t r0 = (size_t)(0 * 1024 + g0 + srow) * 256 + k0 + sk4;
            size_t r1 = (size_t)(1 * 1024 + g0 + srow) * 256 + k0 + sk4;
            size_t r2 = (size_t)(2 * 1024 + g0 + srow) * 256 + k0 + sk4;
            nb0h = ldu4(&a.wihh[r0]); nb0l = ldu4(&a.wihl[r0]);
            nb1h = ldu4(&a.wihh[r1]); nb1l = ldu4(&a.wihl[r1]);
            nb2h = ldu4(&a.wihh[r2]); nb2l = ldu4(&a.wihl[r2]);
          } else {
            #pragma unroll
            for (int g = 0; g < 3; ++g) {
              float4 w4 = *(const float4*)&a.wih[(size_t)(g * 1024 + g0 + srow) * 256 + k0 + sk4];
              u16 h0,l0,h1,l1,h2,l2,h3,l3;
              split2(w4.x,h0,l0); split2(w4.y,h1,l1); split2(w4.z,h2,l2); split2(w4.w,h3,l3);
              ushort4 hh = make_ushort4(h0,h1,h2,h3), ll = make_ushort4(l0,l1,l2,l3);
              if (g == 0) { nb0h = hh; nb0l = ll; }
              else if (g == 1) { nb1h = hh; nb1l = ll; }
              else { nb2h = hh; nb2l = ll; }
            }
          }
        }
        const int fa = db * 1280 + (wm + lr) * 40 + lq * 8;
        s16x8 ah = *(const s16x8*)&sAh[fa];
        s16x8 al = *(const s16x8*)&sAl[fa];
        #pragma unroll
        for (int g = 0; g < 3; ++g) {
          const int fb = db * 3840 + g * 1280 + (wn + lr) * 40 + lq * 8;
          s16x8 bh = *(const s16x8*)&sBh[fb];
          s16x8 bl = *(const s16x8*)&sBl[fb];
          f32x4 c = (g == 0) ? aR : (g == 1) ? aZ : aNi;
          c = mfma16(ah, bh, c); c = mfma16(ah, bl, c); c = mfma16(al, bh, c);
          if (g == 0) aR = c; else if (g == 1) aZ = c; else aNi = c;
        }
        if (pf) {
          stu4(&sAh[nb * 1280 + sidx], nah); stu4(&sAl[nb * 1280 + sidx], nal);
          stu4(&sBh[nb * 3840 + 0 * 1280 + sidx], nb0h); stu4(&sBl[nb * 3840 + 0 * 1280 + sidx], nb0l);
          stu4(&sBh[nb * 3840 + 1 * 1280 + sidx], nb1h); stu4(&sBl[nb * 3840 + 1 * 1280 + sidx], nb1l);
          stu4(&sBh[nb * 3840 + 2 * 1280 + sidx], nb2h); stu4(&sBl[nb * 3840 + 2 * 1280 + sidx], nb2l);
        }
        __syncthreads();
      }
      // epilogue: pointwise GRU + outputs + next state
      #pragma unroll
      for (int r = 0; r < 4; ++r) {
        const int row = m0 + wm + lq * 4 + r;
        const int jg = g0 + wn + lr;
        float rr = sigmoidf_(aR[r] + a.bih[jg] + a.bhh[jg]);
        float zz = sigmoidf_(aZ[r] + a.bih[1024 + jg] + a.bhh[1024 + jg]);
        float nn = tanhf(aNi[r] + a.bih[2048 + jg] + rr * (aNh[r] + a.bhh[2048 + jg]));
        size_t oh = (size_t)row * HID + jg;
        float hv = p2f(chi[oh], clo[oh]);
        float val = (1.f - zz) * nn + zz * hv;
        a.out[(size_t)LSEQ * BATCH * LAT + oh] = val;       // output 1 (new_h)
        if (jg < LAT) {
          a.out[((size_t)t * BATCH + row) * LAT + jg] = val; // output 0
          u16 h, l; split2(val, h, l);
          nhi[oh] = h; nhi[oh + LAT] = h;
          nlo[oh] = l; nlo[oh + LAT] = l;
        }
      }
    }
    gbar();
  }
}

extern "C" void kernel_launch(void* const* d_in, const int* in_sizes, int n_in,
                              void* d_out, int out_size, void* d_ws, size_t ws_size,
                              hipStream_t stream)
{
  const float* data = (const float*)d_in[0];
  const float* w1   = (const float*)d_in[1];
  const float* b1   = (const float*)d_in[2];
  const float* w2   = (const float*)d_in[3];
  const float* b2   = (const float*)d_in[4];
  const float* wih  = (const float*)d_in[5];
  const float* bih  = (const float*)d_in[6];
  const float* whh  = (const float*)d_in[7];
  const float* bhh  = (const float*)d_in[8];
  float* out = (float*)d_out;

  char* w = (char*)d_ws;
  auto alloc = [&](size_t bytes) { char* p = w; w += bytes; return p; };
  u16* w1h = (u16*)alloc((size_t)512 * 1024 * 2);   // [1024][512] planes
  u16* w1l = (u16*)alloc((size_t)512 * 1024 * 2);
  u16* w2h = (u16*)alloc((size_t)512 * 1024 * 2);   // [512][1024] planes
  u16* w2l = (u16*)alloc((size_t)512 * 1024 * 2);
  u16* c0h = (u16*)alloc((size_t)BATCH * HID * 2);
  u16* c0l = (u16*)alloc((size_t)BATCH * HID * 2);
  u16* c1h = (u16*)alloc((size_t)BATCH * HID * 2);
  u16* c1l = (u16*)alloc((size_t)BATCH * HID * 2);
  u16* h1h = (u16*)alloc((size_t)BATCH * HID * 2);
  u16* h1l = (u16*)alloc((size_t)BATCH * HID * 2);
  unsigned* bar = (unsigned*)alloc(128);
  size_t base = (size_t)(w - (char*)d_ws);
  size_t need_opt = base + 2 * ((size_t)3072 * 1024 * 2) + 2 * ((size_t)3072 * 256 * 2);
  bool planes = ws_size >= need_opt;
  u16 *whhh = nullptr, *whhl = nullptr, *wihh = nullptr, *wihl = nullptr;
  if (planes) {
    whhh = (u16*)alloc((size_t)3072 * 1024 * 2);
    whhl = (u16*)alloc((size_t)3072 * 1024 * 2);
    wihh = (u16*)alloc((size_t)3072 * 256 * 2);
    wihl = (u16*)alloc((size_t)3072 * 256 * 2);
  }

  tsplit_k<<<dim3(512 / 32, 1024 / 32), 256, 0, stream>>>(w1, w1h, w1l, 512, 1024);
  tsplit_k<<<dim3(1024 / 32, 512 / 32), 256, 0, stream>>>(w2, w2h, w2l, 1024, 512);
  if (planes) {
    esplit_k<<<dim3((3072 * 1024) / 1024), 256, 0, stream>>>(whh, whhh, whhl);
    esplit_k<<<dim3((3072 * 256) / 1024), 256, 0, stream>>>(wih, wihh, wihl);
  }
  init_k<<<dim3(256), 256, 0, stream>>>(c0h, c0l, bar);

  MegaArgs ma;
  ma.data = data;
  ma.w1h = w1h; ma.w1l = w1l; ma.w2h = w2h; ma.w2l = w2l;
  ma.b1 = b1; ma.b2 = b2;
  ma.whh = whh; ma.whhh = whhh; ma.whhl = whhl;
  ma.wih = wih; ma.wihh = wihh; ma.wihl = wihl;
  ma.bih = bih; ma.bhh = bhh;
  ma.c0h = c0h; ma.c0l = c0l; ma.c1h = c1h; ma.c1l = c1l;
  ma.h1h = h1h; ma.h1l = h1l;
  ma.bar = bar; ma.out = out;
  void* kargs[] = { &ma };
  hipLaunchCooperativeKernel(
      planes ? reinterpret_cast<void*>(mega_k<true>) : reinterpret_cast<void*>(mega_k<false>),
      dim3(NBLK), dim3(256), kargs, 0, stream);
}

// Round 6
// 4865.374 us; speedup vs baseline: 2.4212x; 2.4212x over previous
//
#include <hip/hip_runtime.h>

#define LSEQ 50
#define BATCH 256
#define DIN 256
#define LAT 512
#define HID 1024
#define ROWSTRIDE 257  // D_IN + 1 (dt channel)

typedef __attribute__((ext_vector_type(8))) short s16x8;
typedef __attribute__((ext_vector_type(4))) float f32x4;
using u16 = unsigned short;

__device__ __forceinline__ u16 bfhi(float v) {
  union { float f; unsigned u; } a; a.f = v;
  return (u16)((a.u + 0x7FFFu + ((a.u >> 16) & 1u)) >> 16);
}
__device__ __forceinline__ void split2(float v, u16& h, u16& l) {
  u16 hu = bfhi(v);
  union { unsigned u; float f; } hf; hf.u = ((unsigned)hu) << 16;
  h = hu; l = bfhi(v - hf.f);
}
__device__ __forceinline__ float p2f(u16 h, u16 l) {
  union { unsigned u; float f; } a, b;
  a.u = ((unsigned)h) << 16; b.u = ((unsigned)l) << 16;
  return a.f + b.f;
}
__device__ __forceinline__ float sigmoidf_(float x) { return 1.f / (1.f + __expf(-x)); }
__device__ __forceinline__ f32x4 mfma16(s16x8 a, s16x8 b, f32x4 c) {
  return __builtin_amdgcn_mfma_f32_16x16x32_bf16(a, b, c, 0, 0, 0);
}
__device__ __forceinline__ ushort4 ldu4(const u16* p) { return *(const ushort4*)p; }
__device__ __forceinline__ void stu4(u16* p, ushort4 v) { *(ushort4*)p = v; }

// ---------- preprocessing ----------
__global__ __launch_bounds__(256) void tsplit_k(const float* __restrict__ W,
    u16* __restrict__ Thi, u16* __restrict__ Tlo, int K, int N)
{
  __shared__ unsigned Ts[32][33];
  const int bk = blockIdx.x * 32, bn = blockIdx.y * 32;
  const int t = threadIdx.x;
  const int n_l = t & 31, k_l4 = (t >> 5) * 4;
  #pragma unroll
  for (int i = 0; i < 4; i++) {
    float v = W[(size_t)(bk + k_l4 + i) * N + bn + n_l];
    u16 h, l; split2(v, h, l);
    Ts[k_l4 + i][n_l] = ((unsigned)h << 16) | l;
  }
  __syncthreads();
  const int k_l = t & 31, n_l2 = t >> 5;
  #pragma unroll
  for (int i = 0; i < 4; i++) {
    int nn = n_l2 + 8 * i;
    unsigned u = Ts[k_l][nn];
    size_t o = (size_t)(bn + nn) * K + bk + k_l;
    Thi[o] = (u16)(u >> 16);
    Tlo[o] = (u16)(u & 0xFFFFu);
  }
}

__global__ __launch_bounds__(256) void esplit_k(const float* __restrict__ W,
    u16* __restrict__ Phi, u16* __restrict__ Plo)
{
  size_t i4 = ((size_t)blockIdx.x * 256 + threadIdx.x) * 4;
  float4 v = *(const float4*)&W[i4];
  u16 h[4], l[4];
  split2(v.x, h[0], l[0]); split2(v.y, h[1], l[1]);
  split2(v.z, h[2], l[2]); split2(v.w, h[3], l[3]);
  *(ushort4*)&Phi[i4] = make_ushort4(h[0], h[1], h[2], h[3]);
  *(ushort4*)&Plo[i4] = make_ushort4(l[0], l[1], l[2], l[3]);
}

__global__ __launch_bounds__(256) void init_k(u16* __restrict__ c0h, u16* __restrict__ c0l)
{
  size_t i4 = ((size_t)blockIdx.x * 256 + threadIdx.x) * 4;  // 256 blocks -> 256*1024
  *(ushort4*)&c0h[i4] = make_ushort4(0, 0, 0, 0);
  *(ushort4*)&c0l[i4] = make_ushort4(0, 0, 0, 0);
}

// ---------- double-buffered split-bf16 GEMM (32x32 block tile, 4 waves) ----------
// EPI 1: O planes = split(tanh(acc + bias))
// EPI 2: y = p2f(O planes) + (acc + bias)*dt/3; O planes = split(y)
template<int EPI>
__device__ __forceinline__ void gemm_phase(
    u16* Sah, u16* Sal, int sA, u16* Sbh, u16* Sbl, int sB,
    const u16* __restrict__ Ahi, const u16* __restrict__ Alo, int ldA, int m0,
    const u16* __restrict__ Bhi, const u16* __restrict__ Blo, int ldB, int n0,
    int K, const float* __restrict__ bias,
    u16* __restrict__ Ohi, u16* __restrict__ Olo,
    const float* __restrict__ data, int t, int tid)
{
  const int lane = tid & 63, wave = tid >> 6;
  const int wm = (wave >> 1) << 4, wn = (wave & 1) << 4;
  const int lr = lane & 15, lq = lane >> 4;
  const int srow = tid >> 3, sk4 = (tid & 7) << 2;
  const int sidx = srow * 40 + sk4;
  f32x4 acc = {0.f, 0.f, 0.f, 0.f};
  {
    size_t oa = (size_t)(m0 + srow) * ldA + sk4;
    size_t ob = (size_t)(n0 + srow) * ldB + sk4;
    stu4(&Sah[sidx], ldu4(&Ahi[oa])); stu4(&Sal[sidx], ldu4(&Alo[oa]));
    stu4(&Sbh[sidx], ldu4(&Bhi[ob])); stu4(&Sbl[sidx], ldu4(&Blo[ob]));
  }
  __syncthreads();
  const int niter = K >> 5;
  for (int it = 0; it < niter; ++it) {
    const int db = it & 1, nb = db ^ 1;
    const bool pf = (it + 1 < niter);
    ushort4 nah, nal, nbh, nbl;
    if (pf) {
      const int k0 = (it + 1) << 5;
      size_t oa = (size_t)(m0 + srow) * ldA + k0 + sk4;
      size_t ob = (size_t)(n0 + srow) * ldB + k0 + sk4;
      nah = ldu4(&Ahi[oa]); nal = ldu4(&Alo[oa]);
      nbh = ldu4(&Bhi[ob]); nbl = ldu4(&Blo[ob]);
    }
    const int fa = db * sA + (wm + lr) * 40 + lq * 8;
    const int fb = db * sB + (wn + lr) * 40 + lq * 8;
    s16x8 ah = *(const s16x8*)&Sah[fa];
    s16x8 al = *(const s16x8*)&Sal[fa];
    s16x8 bh = *(const s16x8*)&Sbh[fb];
    s16x8 bl = *(const s16x8*)&Sbl[fb];
    acc = mfma16(ah, bh, acc);
    acc = mfma16(ah, bl, acc);
    acc = mfma16(al, bh, acc);
    if (pf) {
      stu4(&Sah[nb * sA + sidx], nah); stu4(&Sal[nb * sA + sidx], nal);
      stu4(&Sbh[nb * sB + sidx], nbh); stu4(&Sbl[nb * sB + sidx], nbl);
    }
    __syncthreads();
  }
  #pragma unroll
  for (int r = 0; r < 4; ++r) {
    const int row = m0 + wm + lq * 4 + r;
    const int col = n0 + wn + lr;
    float v = acc[r] + bias[col];
    size_t o = (size_t)row * HID + col;
    if (EPI == 1) {
      float h1 = tanhf(v);
      u16 h, l; split2(h1, h, l);
      Ohi[o] = h; Olo[o] = l;
    } else {
      float dt3 = data[(size_t)(t * BATCH + row) * ROWSTRIDE + DIN] * (1.f / 3.f);
      float y = p2f(Ohi[o], Olo[o]) + v * dt3;
      u16 h, l; split2(y, h, l);
      Ohi[o] = h; Olo[o] = l;
    }
  }
}

// G1: grid(32,8)  h1 = tanh(y @ w1 + b1)
// G2: grid(16,8)  y += (h1 @ w2 + b2)*dt/3
template<int EPI>
__global__ __launch_bounds__(256) void mlp_k(
    const u16* __restrict__ Ahi, const u16* __restrict__ Alo,
    const u16* __restrict__ Bhi, const u16* __restrict__ Blo, int ldB,
    const float* __restrict__ bias,
    u16* __restrict__ Ohi, u16* __restrict__ Olo,
    int K, const float* __restrict__ data, int t)
{
  __shared__ u16 sAh[2 * 1280], sAl[2 * 1280], sBh[2 * 1280], sBl[2 * 1280];
  const int n0 = blockIdx.x << 5, m0 = blockIdx.y << 5;
  gemm_phase<EPI>(sAh, sAl, 1280, sBh, sBl, 1280,
                  Ahi, Alo, HID, m0, Bhi, Blo, ldB, n0, K,
                  bias, Ohi, Olo, data, t, threadIdx.x);
}

// ---------- fused GRU: gh(K=1024) + gi(K=256) + pointwise + outputs; grid(32,8) ----------
template<bool PLANES>
__global__ __launch_bounds__(256) void gruf_k(
    const u16* __restrict__ chi, const u16* __restrict__ clo,   // hcat planes [256][1024]
    const float* __restrict__ whh, const u16* __restrict__ whhh, const u16* __restrict__ whhl,
    const float* __restrict__ wih, const u16* __restrict__ wihh, const u16* __restrict__ wihl,
    const float* __restrict__ bih, const float* __restrict__ bhh,
    const float* __restrict__ data, int t,
    u16* __restrict__ nhi, u16* __restrict__ nlo,
    float* __restrict__ out)
{
  __shared__ u16 sAh[2 * 1280], sAl[2 * 1280];
  __shared__ u16 sBh[2 * 3840], sBl[2 * 3840];
  const int tid = threadIdx.x;
  const int g0 = blockIdx.x << 5, m0 = blockIdx.y << 5;
  const int lane = tid & 63, wave = tid >> 6;
  const int wm = (wave >> 1) << 4, wn = (wave & 1) << 4;
  const int lr = lane & 15, lq = lane >> 4;
  const int srow = tid >> 3, sk4 = (tid & 7) << 2;
  const int sidx = srow * 40 + sk4;

  f32x4 aR = {0,0,0,0}, aZ = {0,0,0,0}, aNh = {0,0,0,0}, aNi = {0,0,0,0};
  // phase 0 preload (K-tile 0)
  {
    size_t oa = (size_t)(m0 + srow) * HID + sk4;
    stu4(&sAh[sidx], ldu4(&chi[oa])); stu4(&sAl[sidx], ldu4(&clo[oa]));
    #pragma unroll
    for (int g = 0; g < 3; ++g) {
      const size_t rrow = (size_t)(g * 1024 + g0 + srow);
      if (PLANES) {
        size_t ob = rrow * 1024 + sk4;
        stu4(&sBh[g * 1280 + sidx], ldu4(&whhh[ob]));
        stu4(&sBl[g * 1280 + sidx], ldu4(&whhl[ob]));
      } else {
        float4 w4 = *(const float4*)&whh[rrow * 1024 + sk4];
        u16 h0,l0,h1,l1,h2,l2,h3,l3;
        split2(w4.x,h0,l0); split2(w4.y,h1,l1); split2(w4.z,h2,l2); split2(w4.w,h3,l3);
        stu4(&sBh[g * 1280 + sidx], make_ushort4(h0,h1,h2,h3));
        stu4(&sBl[g * 1280 + sidx], make_ushort4(l0,l1,l2,l3));
      }
    }
  }
  __syncthreads();
  for (int it = 0; it < 32; ++it) {
    const int db = it & 1, nb = db ^ 1;
    const bool pf = (it + 1 < 32);
    ushort4 nah, nal, nb0h, nb0l, nb1h, nb1l, nb2h, nb2l;
    if (pf) {
      const int k0 = (it + 1) << 5;
      size_t oa = (size_t)(m0 + srow) * HID + k0 + sk4;
      nah = ldu4(&chi[oa]); nal = ldu4(&clo[oa]);
      if (PLANES) {
        size_t r0 = (size_t)(0 * 1024 + g0 + srow) * 1024 + k0 + sk4;
        size_t r1 = (size_t)(1 * 1024 + g0 + srow) * 1024 + k0 + sk4;
        size_t r2 = (size_t)(2 * 1024 + g0 + srow) * 1024 + k0 + sk4;
        nb0h = ldu4(&whhh[r0]); nb0l = ldu4(&whhl[r0]);
        nb1h = ldu4(&whhh[r1]); nb1l = ldu4(&whhl[r1]);
        nb2h = ldu4(&whhh[r2]); nb2l = ldu4(&whhl[r2]);
      } else {
        #pragma unroll
        for (int g = 0; g < 3; ++g) {
          float4 w4 = *(const float4*)&whh[(size_t)(g * 1024 + g0 + srow) * 1024 + k0 + sk4];
          u16 h0,l0,h1,l1,h2,l2,h3,l3;
          split2(w4.x,h0,l0); split2(w4.y,h1,l1); split2(w4.z,h2,l2); split2(w4.w,h3,l3);
          ushort4 hh = make_ushort4(h0,h1,h2,h3), ll = make_ushort4(l0,l1,l2,l3);
          if (g == 0) { nb0h = hh; nb0l = ll; }
          else if (g == 1) { nb1h = hh; nb1l = ll; }
          else { nb2h = hh; nb2l = ll; }
        }
      }
    }
    const int fa = db * 1280 + (wm + lr) * 40 + lq * 8;
    s16x8 ah = *(const s16x8*)&sAh[fa];
    s16x8 al = *(const s16x8*)&sAl[fa];
    #pragma unroll
    for (int g = 0; g < 3; ++g) {
      const int fb = db * 3840 + g * 1280 + (wn + lr) * 40 + lq * 8;
      s16x8 bh = *(const s16x8*)&sBh[fb];
      s16x8 bl = *(const s16x8*)&sBl[fb];
      f32x4 c = (g == 0) ? aR : (g == 1) ? aZ : aNh;
      c = mfma16(ah, bh, c); c = mfma16(ah, bl, c); c = mfma16(al, bh, c);
      if (g == 0) aR = c; else if (g == 1) aZ = c; else aNh = c;
    }
    if (pf) {
      stu4(&sAh[nb * 1280 + sidx], nah); stu4(&sAl[nb * 1280 + sidx], nal);
      stu4(&sBh[nb * 3840 + 0 * 1280 + sidx], nb0h); stu4(&sBl[nb * 3840 + 0 * 1280 + sidx], nb0l);
      stu4(&sBh[nb * 3840 + 1 * 1280 + sidx], nb1h); stu4(&sBl[nb * 3840 + 1 * 1280 + sidx], nb1l);
      stu4(&sBh[nb * 3840 + 2 * 1280 + sidx], nb2h); stu4(&sBl[nb * 3840 + 2 * 1280 + sidx], nb2l);
    }
    __syncthreads();
  }
  // phase 1: gi (x_t split on the fly), K = 256
  {
    const float* xp = &data[(size_t)(t * BATCH + m0 + srow) * ROWSTRIDE + sk4];
    u16 xh[4], xl[4];
    #pragma unroll
    for (int i = 0; i < 4; i++) split2(xp[i], xh[i], xl[i]);
    stu4(&sAh[sidx], make_ushort4(xh[0], xh[1], xh[2], xh[3]));
    stu4(&sAl[sidx], make_ushort4(xl[0], xl[1], xl[2], xl[3]));
    #pragma unroll
    for (int g = 0; g < 3; ++g) {
      const size_t rrow = (size_t)(g * 1024 + g0 + srow);
      if (PLANES) {
        size_t ob = rrow * 256 + sk4;
        stu4(&sBh[g * 1280 + sidx], ldu4(&wihh[ob]));
        stu4(&sBl[g * 1280 + sidx], ldu4(&wihl[ob]));
      } else {
        float4 w4 = *(const float4*)&wih[rrow * 256 + sk4];
        u16 h0,l0,h1,l1,h2,l2,h3,l3;
        split2(w4.x,h0,l0); split2(w4.y,h1,l1); split2(w4.z,h2,l2); split2(w4.w,h3,l3);
        stu4(&sBh[g * 1280 + sidx], make_ushort4(h0,h1,h2,h3));
        stu4(&sBl[g * 1280 + sidx], make_ushort4(l0,l1,l2,l3));
      }
    }
  }
  __syncthreads();
  for (int it = 0; it < 8; ++it) {
    const int db = it & 1, nb = db ^ 1;
    const bool pf = (it + 1 < 8);
    ushort4 nah, nal, nb0h, nb0l, nb1h, nb1l, nb2h, nb2l;
    if (pf) {
      const int k0 = (it + 1) << 5;
      const float* xp = &data[(size_t)(t * BATCH + m0 + srow) * ROWSTRIDE + k0 + sk4];
      u16 xh[4], xl[4];
      #pragma unroll
      for (int i = 0; i < 4; i++) split2(xp[i], xh[i], xl[i]);
      nah = make_ushort4(xh[0], xh[1], xh[2], xh[3]);
      nal = make_ushort4(xl[0], xl[1], xl[2], xl[3]);
      if (PLANES) {
        size_t r0 = (size_t)(0 * 1024 + g0 + srow) * 256 + k0 + sk4;
        size_t r1 = (size_t)(1 * 1024 + g0 + srow) * 256 + k0 + sk4;
        size_t r2 = (size_t)(2 * 1024 + g0 + srow) * 256 + k0 + sk4;
        nb0h = ldu4(&wihh[r0]); nb0l = ldu4(&wihl[r0]);
        nb1h = ldu4(&wihh[r1]); nb1l = ldu4(&wihl[r1]);
        nb2h = ldu4(&wihh[r2]); nb2l = ldu4(&wihl[r2]);
      } else {
        #pragma unroll
        for (int g = 0; g < 3; ++g) {
          float4 w4 = *(const float4*)&wih[(size_t)(g * 1024 + g0 + srow) * 256 + k0 + sk4];
          u16 h0,l0,h1,l1,h2,l2,h3,l3;
          split2(w4.x,h0,l0); split2(w4.y,h1,l1); split2(w4.z,h2,l2); split2(w4.w,h3,l3);
          ushort4 hh = make_ushort4(h0,h1,h2,h3), ll = make_ushort4(l0,l1,l2,l3);
          if (g == 0) { nb0h = hh; nb0l = ll; }
          else if (g == 1) { nb1h = hh; nb1l = ll; }
          else { nb2h = hh; nb2l = ll; }
        }
      }
    }
    const int fa = db * 1280 + (wm + lr) * 40 + lq * 8;
    s16x8 ah = *(const s16x8*)&sAh[fa];
    s16x8 al = *(const s16x8*)&sAl[fa];
    #pragma unroll
    for (int g = 0; g < 3; ++g) {
      const int fb = db * 3840 + g * 1280 + (wn + lr) * 40 + lq * 8;
      s16x8 bh = *(const s16x8*)&sBh[fb];
      s16x8 bl = *(const s16x8*)&sBl[fb];
      f32x4 c = (g == 0) ? aR : (g == 1) ? aZ : aNi;
      c = mfma16(ah, bh, c); c = mfma16(ah, bl, c); c = mfma16(al, bh, c);
      if (g == 0) aR = c; else if (g == 1) aZ = c; else aNi = c;
    }
    if (pf) {
      stu4(&sAh[nb * 1280 + sidx], nah); stu4(&sAl[nb * 1280 + sidx], nal);
      stu4(&sBh[nb * 3840 + 0 * 1280 + sidx], nb0h); stu4(&sBl[nb * 3840 + 0 * 1280 + sidx], nb0l);
      stu4(&sBh[nb * 3840 + 1 * 1280 + sidx], nb1h); stu4(&sBl[nb * 3840 + 1 * 1280 + sidx], nb1l);
      stu4(&sBh[nb * 3840 + 2 * 1280 + sidx], nb2h); stu4(&sBl[nb * 3840 + 2 * 1280 + sidx], nb2l);
    }
    __syncthreads();
  }
  // epilogue: pointwise GRU + outputs + next state
  #pragma unroll
  for (int r = 0; r < 4; ++r) {
    const int row = m0 + wm + lq * 4 + r;
    const int jg = g0 + wn + lr;
    float rr = sigmoidf_(aR[r] + bih[jg] + bhh[jg]);
    float zz = sigmoidf_(aZ[r] + bih[1024 + jg] + bhh[1024 + jg]);
    float nn = tanhf(aNi[r] + bih[2048 + jg] + rr * (aNh[r] + bhh[2048 + jg]));
    size_t oh = (size_t)row * HID + jg;
    float hv = p2f(chi[oh], clo[oh]);
    float val = (1.f - zz) * nn + zz * hv;
    out[(size_t)LSEQ * BATCH * LAT + oh] = val;        // output 1 (new_h)
    if (jg < LAT) {
      out[((size_t)t * BATCH + row) * LAT + jg] = val; // output 0
      u16 h, l; split2(val, h, l);
      nhi[oh] = h; nhi[oh + LAT] = h;
      nlo[oh] = l; nlo[oh + LAT] = l;
    }
  }
}

extern "C" void kernel_launch(void* const* d_in, const int* in_sizes, int n_in,
                              void* d_out, int out_size, void* d_ws, size_t ws_size,
                              hipStream_t stream)
{
  const float* data = (const float*)d_in[0];
  const float* w1   = (const float*)d_in[1];
  const float* b1   = (const float*)d_in[2];
  const float* w2   = (const float*)d_in[3];
  const float* b2   = (const float*)d_in[4];
  const float* wih  = (const float*)d_in[5];
  const float* bih  = (const float*)d_in[6];
  const float* whh  = (const float*)d_in[7];
  const float* bhh  = (const float*)d_in[8];
  float* out = (float*)d_out;

  char* w = (char*)d_ws;
  auto alloc = [&](size_t bytes) { char* p = w; w += bytes; return p; };
  u16* w1h = (u16*)alloc((size_t)512 * 1024 * 2);   // [1024 n][512 k] planes
  u16* w1l = (u16*)alloc((size_t)512 * 1024 * 2);
  u16* w2h = (u16*)alloc((size_t)512 * 1024 * 2);   // [512 n][1024 k] planes
  u16* w2l = (u16*)alloc((size_t)512 * 1024 * 2);
  u16* c0h = (u16*)alloc((size_t)BATCH * HID * 2);
  u16* c0l = (u16*)alloc((size_t)BATCH * HID * 2);
  u16* c1h = (u16*)alloc((size_t)BATCH * HID * 2);
  u16* c1l = (u16*)alloc((size_t)BATCH * HID * 2);
  u16* h1h = (u16*)alloc((size_t)BATCH * HID * 2);
  u16* h1l = (u16*)alloc((size_t)BATCH * HID * 2);
  size_t base = (size_t)(w - (char*)d_ws);
  size_t need_opt = base + 2 * ((size_t)3072 * 1024 * 2) + 2 * ((size_t)3072 * 256 * 2);
  bool planes = ws_size >= need_opt;
  u16 *whhh = nullptr, *whhl = nullptr, *wihh = nullptr, *wihl = nullptr;
  if (planes) {
    whhh = (u16*)alloc((size_t)3072 * 1024 * 2);
    whhl = (u16*)alloc((size_t)3072 * 1024 * 2);
    wihh = (u16*)alloc((size_t)3072 * 256 * 2);
    wihl = (u16*)alloc((size_t)3072 * 256 * 2);
  }

  tsplit_k<<<dim3(512 / 32, 1024 / 32), 256, 0, stream>>>(w1, w1h, w1l, 512, 1024);
  tsplit_k<<<dim3(1024 / 32, 512 / 32), 256, 0, stream>>>(w2, w2h, w2l, 1024, 512);
  if (planes) {
    esplit_k<<<dim3((3072 * 1024) / 1024), 256, 0, stream>>>(whh, whhh, whhl);
    esplit_k<<<dim3((3072 * 256) / 1024), 256, 0, stream>>>(wih, wihh, wihl);
  }
  init_k<<<dim3(256), 256, 0, stream>>>(c0h, c0l);

  for (int t = 0; t < LSEQ; ++t) {
    u16* chi = (t & 1) ? c1h : c0h;
    u16* clo = (t & 1) ? c1l : c0l;
    u16* nhi = (t & 1) ? c0h : c1h;
    u16* nlo = (t & 1) ? c0l : c1l;
    for (int s = 0; s < 3; ++s) {
      mlp_k<1><<<dim3(32, 8), 256, 0, stream>>>(chi, clo, w1h, w1l, 512, b1,
                                                h1h, h1l, 512, nullptr, 0);
      mlp_k<2><<<dim3(16, 8), 256, 0, stream>>>(h1h, h1l, w2h, w2l, 1024, b2,
                                                chi, clo, 1024, data, t);
    }
    if (planes)
      gruf_k<true><<<dim3(32, 8), 256, 0, stream>>>(chi, clo,
          whh, whhh, whhl, wih, wihh, wihl, bih, bhh, data, t, nhi, nlo, out);
    else
      gruf_k<false><<<dim3(32, 8), 256, 0, stream>>>(chi, clo,
          whh, whhh, whhl, wih, wihh, wihl, bih, bhh, data, t, nhi, nlo, out);
  }
}